// Round 12
// baseline (695.737 us; speedup 1.0000x reference)
//
#include <hip/hip_runtime.h>
#include <cstdint>

typedef __attribute__((ext_vector_type(8))) _Float16 half8;
typedef __attribute__((ext_vector_type(4))) _Float16 half4;
typedef __attribute__((ext_vector_type(4))) float f32x4;
typedef __attribute__((ext_vector_type(4))) unsigned int u32x4;

// ---------------- prep: build the exact 130 KB LDS image in d_ws ----------------
// bytes [0,131072): 32 fragment planes fi = (L*2+kp)*2 + plane(hi=0,lo=1);
//                   plane layout [mt(4)][lane(64)] x 16B chunks (8 halves, e=0..7)
//                   chunk value: W[mt*16+(lane&15)][ (2kp+(e>>2))*16 + 4*(lane>>4) + (e&3) ]
// bytes [131072,133120): biases f32 [L(8)][feat(64)]
__global__ void prep_weights(const float* __restrict__ cWh, const float* __restrict__ cWo,
                             const float* __restrict__ sWh, const float* __restrict__ sWo,
                             const float* __restrict__ cbh, const float* __restrict__ cbo,
                             const float* __restrict__ sbh, const float* __restrict__ sbo,
                             char* __restrict__ img) {
    int t = blockIdx.x * 256 + threadIdx.x;  // 0..33279
    if (t < 32768) {
        int e = t & 7, mt = (t >> 3) & 3, lane = (t >> 5) & 63, kp = (t >> 11) & 1, L = (t >> 12) & 7;
        const float* src = (L < 3)  ? cWh + L * 4096
                         : (L == 3) ? cWo
                         : (L < 7)  ? sWh + (L - 4) * 4096
                         :            sWo;
        int m = mt * 16 + (lane & 15);
        int k = (2 * kp + (e >> 2)) * 16 + 4 * (lane >> 4) + (e & 3);
        float w = src[m * 64 + k];
        _Float16 hi = (_Float16)w;                 // RTNE hardware cvt
        _Float16 lo = (_Float16)(w - (float)hi);
        _Float16* wf = (_Float16*)img;
        int fi = (L * 2 + kp) * 2;
        wf[((fi * 4 + mt) * 64 + lane) * 8 + e]       = hi;
        wf[(((fi + 1) * 4 + mt) * 64 + lane) * 8 + e] = lo;
    } else if (t < 33280) {
        int b = t - 32768;  // L*64 + feat
        int L = b >> 6, f = b & 63;
        const float* src = (L < 3)  ? cbh + L * 64
                         : (L == 3) ? cbo
                         : (L < 7)  ? sbh + (L - 4) * 64
                         :            sbo;
        ((float*)(img + 131072))[b] = src[f];
    }
}

// build one fp16 B-fragment from two f32x4 acc tiles (k-tiles 2kp, 2kp+1), optional relu
template<bool RELU>
__device__ __forceinline__ half8 cvt_frag(f32x4 a, f32x4 b) {
    half8 r;
#pragma unroll
    for (int i = 0; i < 4; ++i) {
        float va = RELU ? fmaxf(a[i], 0.f) : a[i];
        float vb = RELU ? fmaxf(b[i], 0.f) : b[i];
        r[i]     = (_Float16)va;
        r[i + 4] = (_Float16)vb;
    }
    return r;
}

// ---------------- one MLP layer (32 samples/wave): weights+bias from LDS only ----------------
__device__ __forceinline__ void run_layer(const _Float16* __restrict__ lwf,
                                          const float* __restrict__ lb, int Lid,
                                          int lane, int g4,
                                          const half8 B[2][2], f32x4 acc[4][2]) {
#pragma unroll
    for (int mt = 0; mt < 4; ++mt) {
        f32x4 bb = *(const f32x4*)(lb + Lid * 64 + mt * 16 + g4);
#pragma unroll
        for (int nt = 0; nt < 2; ++nt) acc[mt][nt] = bb;
    }
#pragma unroll
    for (int kp = 0; kp < 2; ++kp) {
        const int fi = (Lid * 2 + kp) * 2;
        half8 Ah[4], Al[4];
#pragma unroll
        for (int mt = 0; mt < 4; ++mt) {
            Ah[mt] = *(const half8*)(lwf + ((fi * 4 + mt) * 64 + lane) * 8);
            Al[mt] = *(const half8*)(lwf + (((fi + 1) * 4 + mt) * 64 + lane) * 8);
        }
#pragma unroll
        for (int nt = 0; nt < 2; ++nt)
#pragma unroll
            for (int mt = 0; mt < 4; ++mt) {
                acc[mt][nt] = __builtin_amdgcn_mfma_f32_16x16x32_f16(Ah[mt], B[kp][nt], acc[mt][nt], 0, 0, 0);
                acc[mt][nt] = __builtin_amdgcn_mfma_f32_16x16x32_f16(Al[mt], B[kp][nt], acc[mt][nt], 0, 0, 0);
            }
    }
}

__device__ __forceinline__ void acc_to_B_relu(const f32x4 acc[4][2], half8 B[2][2]) {
#pragma unroll
    for (int kp = 0; kp < 2; ++kp)
#pragma unroll
        for (int nt = 0; nt < 2; ++nt)
            B[kp][nt] = cvt_frag<true>(acc[2 * kp][nt], acc[2 * kp + 1][nt]);
}

// ---------------- main: persistent blocks (1/CU), 8 tiles each, cross-tile x prefetch ----------------
// 256 blocks x 8 waves; wave owns 32 rows/tile; tile stride = 256 blocks * 256 rows.
#define NTILES 8
#define TILE_ROW_STRIDE (256L * 256L)
__global__ __launch_bounds__(512, 2)
void coupling_main(const float* __restrict__ x, const char* __restrict__ img,
                   float* __restrict__ y, float* __restrict__ logdet) {
    extern __shared__ char smem[];
    {   // cooperative LDS copy of the weight+bias image — ONCE per block
        const u32x4* s = (const u32x4*)img;
        u32x4* d = (u32x4*)smem;
        for (int i = threadIdx.x; i < 8320; i += 512) d[i] = s[i];
    }
    const int lane = threadIdx.x & 63;
    const int wid = threadIdx.x >> 6;
    const int c = lane & 15;
    const int g4 = (lane >> 4) * 4;
    const long row0 = (long)blockIdx.x * 256 + wid * 32;

    // initial prefetch: tile 0's x (raw fp32, 64 regs, stays in flight / in place)
    f32x4 xm[2][4], xt[2][4];
    {
        const float* xr = x + (row0 + c) * 128 + g4;
#pragma unroll
        for (int nt = 0; nt < 2; ++nt)
#pragma unroll
            for (int kt = 0; kt < 4; ++kt) {
                xm[nt][kt] = *(const f32x4*)(xr + nt * 2048 + kt * 16);
                xt[nt][kt] = *(const f32x4*)(xr + nt * 2048 + 64 + kt * 16);
            }
    }
    __syncthreads();
    const _Float16* lwf = (const _Float16*)smem;
    const float* lb = (const float*)(smem + 131072);

    for (int t = 0; t < NTILES; ++t) {
        const long r0 = row0 + (long)t * TILE_ROW_STRIDE;
        const float* xr = x + (r0 + c) * 128 + g4;
        float* yr = y + (r0 + c) * 128 + g4;

        // (a) consume raw x(t): passthrough y[:, :64] + pack to fp16 (32 regs total)
        half8 B0[2][2], xth[2][2];
#pragma unroll
        for (int nt = 0; nt < 2; ++nt) {
#pragma unroll
            for (int kt = 0; kt < 4; ++kt)
                __builtin_nontemporal_store(xm[nt][kt], (f32x4*)(yr + nt * 2048 + kt * 16));
            B0[0][nt]  = cvt_frag<false>(xm[nt][0], xm[nt][1]);
            B0[1][nt]  = cvt_frag<false>(xm[nt][2], xm[nt][3]);
            xth[nt][0] = cvt_frag<false>(xt[nt][0], xt[nt][1]);
            xth[nt][1] = cvt_frag<false>(xt[nt][2], xt[nt][3]);
        }

        // (b) refill raw buffer with tile t+1's x — in flight during the 8-layer compute
        if (t + 1 < NTILES) {
            const float* xrn = xr + TILE_ROW_STRIDE * 128;
#pragma unroll
            for (int nt = 0; nt < 2; ++nt)
#pragma unroll
                for (int kt = 0; kt < 4; ++kt) {
                    xm[nt][kt] = *(const f32x4*)(xrn + nt * 2048 + kt * 16);
                    xt[nt][kt] = *(const f32x4*)(xrn + nt * 2048 + 64 + kt * 16);
                }
        }

        f32x4 acc[4][2];
        half8 B[2][2];

        // cond MLP (ids 0..3) -> shift (parked fp16, 8 regs)
        run_layer(lwf, lb, 0, lane, g4, B0, acc);
        acc_to_B_relu(acc, B);
        run_layer(lwf, lb, 1, lane, g4, B, acc);
        acc_to_B_relu(acc, B);
        run_layer(lwf, lb, 2, lane, g4, B, acc);
        acc_to_B_relu(acc, B);
        run_layer(lwf, lb, 3, lane, g4, B, acc);
        half4 shp[4][2];
#pragma unroll
        for (int mt = 0; mt < 4; ++mt)
#pragma unroll
            for (int nt = 0; nt < 2; ++nt) {
                half4 s;
#pragma unroll
                for (int i = 0; i < 4; ++i) s[i] = (_Float16)acc[mt][nt][i];
                shp[mt][nt] = s;
            }

        // scale MLP (ids 4..7) -> log_scale in acc
        run_layer(lwf, lb, 4, lane, g4, B0, acc);
        acc_to_B_relu(acc, B);
        run_layer(lwf, lb, 5, lane, g4, B, acc);
        acc_to_B_relu(acc, B);
        run_layer(lwf, lb, 6, lane, g4, B, acc);
        acc_to_B_relu(acc, B);
        run_layer(lwf, lb, 7, lane, g4, B, acc);

        // (c) epilogue from registers only: y[:,64:] = x_t*exp(clip(ls)) + shift; logdet
        float pld0 = 0.f, pld1 = 0.f;
#pragma unroll
        for (int nt = 0; nt < 2; ++nt) {
            float psum = 0.f;
#pragma unroll
            for (int mt = 0; mt < 4; ++mt) {
                f32x4 ls = acc[mt][nt];
                psum += ls[0] + ls[1] + ls[2] + ls[3];
                half8 xh = xth[nt][mt >> 1];
                const int o4 = (mt & 1) * 4;
                half4 sp = shp[mt][nt];
                f32x4 o;
#pragma unroll
                for (int i = 0; i < 4; ++i) {
                    float cl = fminf(fmaxf(ls[i], -5.f), 3.f);
                    o[i] = (float)xh[o4 + i] * __expf(cl) + (float)sp[i];
                }
                __builtin_nontemporal_store(o, (f32x4*)(yr + nt * 2048 + 64 + mt * 16));
            }
            if (nt == 0) pld0 = psum; else pld1 = psum;
        }
#pragma unroll
        for (int nt = 0; nt < 2; ++nt) {
            float v = (nt == 0) ? pld0 : pld1;
            v += __shfl_xor(v, 16);
            v += __shfl_xor(v, 32);
            if ((lane >> 4) == 0) logdet[r0 + nt * 16 + c] = v;
        }
    }
}

extern "C" void kernel_launch(void* const* d_in, const int* in_sizes, int n_in,
                              void* d_out, int out_size, void* d_ws, size_t ws_size,
                              hipStream_t stream) {
    const float* x   = (const float*)d_in[0];
    const float* cWh = (const float*)d_in[1];
    const float* cbh = (const float*)d_in[2];
    const float* cWo = (const float*)d_in[3];
    const float* cbo = (const float*)d_in[4];
    const float* sWh = (const float*)d_in[5];
    const float* sbh = (const float*)d_in[6];
    const float* sWo = (const float*)d_in[7];
    const float* sbo = (const float*)d_in[8];

    const int B = in_sizes[0] / 128;  // 524288
    const int LDS_BYTES = 133120;

    char* img = (char*)d_ws;  // 130 KB weight+bias image

    prep_weights<<<130, 256, 0, stream>>>(cWh, cWo, sWh, sWo, cbh, cbo, sbh, sbo, img);

    (void)hipFuncSetAttribute((const void*)coupling_main,
                              hipFuncAttributeMaxDynamicSharedMemorySize, LDS_BYTES);

    float* y = (float*)d_out;
    float* logdet = y + (size_t)B * 128;
    // 256 persistent blocks x 8 tiles x 256 rows = 524288 rows
    coupling_main<<<256, 512, LDS_BYTES, stream>>>(x, img, y, logdet);
}

// Round 13
// 155.378 us; speedup vs baseline: 4.4777x; 4.4777x over previous
//
#include <hip/hip_runtime.h>
#include <cstdint>

typedef __attribute__((ext_vector_type(8))) _Float16 half8;
typedef __attribute__((ext_vector_type(4))) _Float16 half4;
typedef __attribute__((ext_vector_type(4))) float f32x4;

// ---------------- weight prep: fp32 W -> permuted-K fp16 hi/lo A-fragments ----------------
// k-slot (g,e) of k-step kp holds feature f = (2kp + (e>>2))*16 + 4g + (e&3).
// Layout: wf[(Lid*2+kp)*2 + plane][lane][mt][e]  (2048 halves per plane-frag)
__global__ void prep_weights(const float* __restrict__ cWh, const float* __restrict__ cWo,
                             const float* __restrict__ sWh, const float* __restrict__ sWo,
                             _Float16* __restrict__ wf) {
    int t = blockIdx.x * 256 + threadIdx.x;  // 0..32767
    int e    = t & 7;
    int mt   = (t >> 3) & 3;
    int lane = (t >> 5) & 63;
    int kp   = (t >> 11) & 1;
    int L    = (t >> 12) & 7;
    const float* src = (L < 3)  ? cWh + L * 4096
                     : (L == 3) ? cWo
                     : (L < 7)  ? sWh + (L - 4) * 4096
                     :            sWo;
    int m = mt * 16 + (lane & 15);
    int k = (2 * kp + (e >> 2)) * 16 + 4 * (lane >> 4) + (e & 3);
    float w = src[m * 64 + k];
    _Float16 hi = (_Float16)w;            // RTNE hardware cvt
    _Float16 lo = (_Float16)(w - (float)hi);
    int off = lane * 32 + mt * 8 + e;
    int fi = (L * 2 + kp) * 2;
    wf[fi * 2048 + off]       = hi;
    wf[(fi + 1) * 2048 + off] = lo;
}

// build one fp16 B-fragment from two f32x4 acc tiles (k-tiles 2kp, 2kp+1), with optional relu
template<bool RELU>
__device__ __forceinline__ half8 cvt_frag(f32x4 a, f32x4 b) {
    half8 r;
#pragma unroll
    for (int i = 0; i < 4; ++i) {
        float va = RELU ? fmaxf(a[i], 0.f) : a[i];
        float vb = RELU ? fmaxf(b[i], 0.f) : b[i];
        r[i]     = (_Float16)va;
        r[i + 4] = (_Float16)vb;
    }
    return r;
}

// ---------------- one MLP layer (64 samples/wave): 2-term weights x 1-term activations ----------------
__device__ __forceinline__ void run_layer(const _Float16* __restrict__ wf, int Lid,
                                          const float* __restrict__ bias, int lane, int g4,
                                          const half8 B[2][4], f32x4 acc[4][4]) {
#pragma unroll
    for (int mt = 0; mt < 4; ++mt) {
        f32x4 bb = *(const f32x4*)(bias + mt * 16 + g4);
#pragma unroll
        for (int nt = 0; nt < 4; ++nt) acc[mt][nt] = bb;
    }
#pragma unroll
    for (int kp = 0; kp < 2; ++kp) {
        half8 Ah[4], Al[4];
        const _Float16* p = wf + (Lid * 2 + kp) * 4096 + lane * 32;
#pragma unroll
        for (int mt = 0; mt < 4; ++mt) {
            Ah[mt] = *(const half8*)(p + mt * 8);
            Al[mt] = *(const half8*)(p + 2048 + mt * 8);
        }
#pragma unroll
        for (int nt = 0; nt < 4; ++nt)
#pragma unroll
            for (int mt = 0; mt < 4; ++mt) {
                acc[mt][nt] = __builtin_amdgcn_mfma_f32_16x16x32_f16(Ah[mt], B[kp][nt], acc[mt][nt], 0, 0, 0);
                acc[mt][nt] = __builtin_amdgcn_mfma_f32_16x16x32_f16(Al[mt], B[kp][nt], acc[mt][nt], 0, 0, 0);
            }
    }
}

__device__ __forceinline__ void acc_to_B_relu(const f32x4 acc[4][4], half8 B[2][4]) {
#pragma unroll
    for (int kp = 0; kp < 2; ++kp)
#pragma unroll
        for (int nt = 0; nt < 4; ++nt)
            B[kp][nt] = cvt_frag<true>(acc[2 * kp][nt], acc[2 * kp + 1][nt]);
}

// ---------------- main: 1 wave = 64 rows; x_t DMA'd to LDS at prologue (zero VGPR) ----------------
// LDS x_t layout: row r (0..63) at r*256B; 16B chunk j stored at slot s = j ^ (r&7)
// (global source pre-swizzled so epilogue reads spread across banks).
__global__ __launch_bounds__(64, 2)
void coupling_main(const float* __restrict__ x,
                   const float* __restrict__ cbh, const float* __restrict__ cbo,
                   const float* __restrict__ sbh, const float* __restrict__ sbo,
                   const _Float16* __restrict__ wf,
                   float* __restrict__ y, float* __restrict__ logdet) {
    __shared__ float xstage[4096];  // 16 KB: x_transform[64][64] (chunk-swizzled)
    const int lane = threadIdx.x;
    const int c = lane & 15;
    const int g = lane >> 4;
    const int g4 = g * 4;
    const long row0 = (long)blockIdx.x * 64;
    const float* xr = x + (row0 + c) * 128 + g4;
    float* yr = y + (row0 + c) * 128 + g4;

    // (1) x_masked register loads (16 x 16B) — issued first so their waitcnt
    //     leaves the DMA below still outstanding
    f32x4 xm[4][4];
#pragma unroll
    for (int nt = 0; nt < 4; ++nt)
#pragma unroll
        for (int kt = 0; kt < 4; ++kt)
            xm[nt][kt] = *(const f32x4*)(xr + nt * 2048 + kt * 16);

    // (2) DMA x_transform -> LDS: 16 x global_load_lds_dwordx4 (no VGPR destination).
    //     Instr i stages rows [4i, 4i+4): lane l -> row 4i + (l>>4), dest slot l&15,
    //     global chunk j = (l&15) ^ (row&7).
    {
        const int rr = lane >> 4;
        const int s  = lane & 15;
#pragma unroll
        for (int i = 0; i < 16; ++i) {
            const int r = i * 4 + rr;
            const int j = s ^ (r & 7);
            const float* src = x + (row0 + r) * 128 + 64 + j * 4;
            __builtin_amdgcn_global_load_lds(
                (const __attribute__((address_space(1))) void*)src,
                (__attribute__((address_space(3))) void*)(xstage + i * 256),
                16, 0, 0);
        }
    }

    // (3) passthrough y[:, :64] + build B0 frags (parked, 32 regs)
    half8 B0[2][4];
#pragma unroll
    for (int nt = 0; nt < 4; ++nt) {
#pragma unroll
        for (int kt = 0; kt < 4; ++kt)
            __builtin_nontemporal_store(xm[nt][kt], (f32x4*)(yr + nt * 2048 + kt * 16));
        B0[0][nt] = cvt_frag<false>(xm[nt][0], xm[nt][1]);
        B0[1][nt] = cvt_frag<false>(xm[nt][2], xm[nt][3]);
    }

    f32x4 acc[4][4];
    half8 B[2][4];

    // cond MLP (ids 0..3) -> shift (parked as fp16, 32 regs)
    run_layer(wf, 0, cbh,       lane, g4, B0, acc);
    acc_to_B_relu(acc, B);
    run_layer(wf, 1, cbh + 64,  lane, g4, B, acc);
    acc_to_B_relu(acc, B);
    run_layer(wf, 2, cbh + 128, lane, g4, B, acc);
    acc_to_B_relu(acc, B);
    run_layer(wf, 3, cbo,       lane, g4, B, acc);
    half4 shp[4][4];
#pragma unroll
    for (int mt = 0; mt < 4; ++mt)
#pragma unroll
        for (int nt = 0; nt < 4; ++nt) {
            half4 s;
#pragma unroll
            for (int i = 0; i < 4; ++i) s[i] = (_Float16)acc[mt][nt][i];
            shp[mt][nt] = s;
        }

    // scale MLP (ids 4..7) -> log_scale in acc
    run_layer(wf, 4, sbh,       lane, g4, B0, acc);
    acc_to_B_relu(acc, B);
    run_layer(wf, 5, sbh + 64,  lane, g4, B, acc);
    acc_to_B_relu(acc, B);
    run_layer(wf, 6, sbh + 128, lane, g4, B, acc);
    acc_to_B_relu(acc, B);
    run_layer(wf, 7, sbo,       lane, g4, B, acc);

    // (4) drain the DMA (completed long ago, during the MLP), then epilogue from LDS
    asm volatile("s_waitcnt vmcnt(0)" ::: "memory");
    __builtin_amdgcn_sched_barrier(0);

    float pld0 = 0.f, pld1 = 0.f, pld2 = 0.f, pld3 = 0.f;
#pragma unroll
    for (int nt = 0; nt < 4; ++nt) {
        float psum = 0.f;
        const int r = nt * 16 + c;
#pragma unroll
        for (int mt = 0; mt < 4; ++mt) {
            f32x4 ls = acc[mt][nt];
            psum += ls[0] + ls[1] + ls[2] + ls[3];
            const int j = (mt * 4 + g) ^ (r & 7);
            f32x4 xt = *(const f32x4*)(xstage + r * 64 + j * 4);
            half4 sp = shp[mt][nt];
            f32x4 o;
#pragma unroll
            for (int i = 0; i < 4; ++i) {
                float cl = fminf(fmaxf(ls[i], -5.f), 3.f);
                o[i] = xt[i] * __expf(cl) + (float)sp[i];
            }
            __builtin_nontemporal_store(o, (f32x4*)(yr + nt * 2048 + 64 + mt * 16));
        }
        if (nt == 0) pld0 = psum; else if (nt == 1) pld1 = psum;
        else if (nt == 2) pld2 = psum; else pld3 = psum;
    }
#pragma unroll
    for (int nt = 0; nt < 4; ++nt) {
        float v = (nt == 0) ? pld0 : (nt == 1) ? pld1 : (nt == 2) ? pld2 : pld3;
        v += __shfl_xor(v, 16);
        v += __shfl_xor(v, 32);
        if ((lane >> 4) == 0) logdet[row0 + nt * 16 + c] = v;
    }
}

extern "C" void kernel_launch(void* const* d_in, const int* in_sizes, int n_in,
                              void* d_out, int out_size, void* d_ws, size_t ws_size,
                              hipStream_t stream) {
    const float* x   = (const float*)d_in[0];
    const float* cWh = (const float*)d_in[1];
    const float* cbh = (const float*)d_in[2];
    const float* cWo = (const float*)d_in[3];
    const float* cbo = (const float*)d_in[4];
    const float* sWh = (const float*)d_in[5];
    const float* sbh = (const float*)d_in[6];
    const float* sWo = (const float*)d_in[7];
    const float* sbo = (const float*)d_in[8];

    const int B = in_sizes[0] / 128;  // 524288

    _Float16* wf = (_Float16*)d_ws;  // 8 layers * 2 kp * 2 planes * 2048 halves = 128 KB

    prep_weights<<<128, 256, 0, stream>>>(cWh, cWo, sWh, sWo, wf);

    float* y = (float*)d_out;
    float* logdet = y + (size_t)B * 128;
    coupling_main<<<B / 64, 64, 0, stream>>>(x, cbh, cbo, sbh, sbo, wf, y, logdet);
}